// Round 17
// baseline (160.648 us; speedup 1.0000x reference)
//
#include <hip/hip_runtime.h>
#include <cstdint>
#include <cstddef>

#define SLEN 2048
#define NB 2
#define NH 32
#define NKV 8
#define HD 64
#define MROWS 4096   // NB*SLEN
#define QDIM 2048    // NH*HD
#define KVDIM 512    // NKV*HD
#define WINH 256     // WIN/2

typedef float f32x4 __attribute__((ext_vector_type(4)));
typedef __bf16 bf16x8 __attribute__((ext_vector_type(8)));

__device__ __forceinline__ unsigned short f2bf(float f) {
  union { float f; unsigned u; } v; v.f = f;
  unsigned r = v.u + 0x7fffu + ((v.u >> 16) & 1u);
  return (unsigned short)(r >> 16);
}
__device__ __forceinline__ float bf2f(unsigned short h) {
  union { unsigned u; float f; } v; v.u = ((unsigned)h) << 16;
  return v.f;
}
__device__ __forceinline__ unsigned pk2(float a, float b) {
  return (unsigned)f2bf(a) | ((unsigned)f2bf(b) << 16);
}
// HW packed fp32->bf16 (RNE), 1 inst per pair
__device__ __forceinline__ unsigned cvtpk(float a, float b) {
  unsigned r;
  asm("v_cvt_pk_bf16_f32 %0, %1, %2" : "=v"(r) : "v"(a), "v"(b));
  return r;
}
__device__ __forceinline__ uint4 cvt16(float4 a, float4 b) {
  uint4 u;
  u.x = pk2(a.x, a.y); u.y = pk2(a.z, a.w);
  u.z = pk2(b.x, b.y); u.w = pk2(b.z, b.w);
  return u;
}
// async global->LDS, 16B per lane; LDS dest is wave-uniform base + lane*16
__device__ __forceinline__ void async16(const unsigned short* g, unsigned short* l) {
  __builtin_amdgcn_global_load_lds(
      (const __attribute__((address_space(1))) unsigned int*)g,
      (__attribute__((address_space(3))) unsigned int*)l, 16, 0, 0);
}

// ---------------- merged conversions + RoPE table --------------------------
// units: [0,1048576) x->xb (x8), [.., 1835008) wqkv->wqkvb (x8),
// [.., 1900544) rope table entries.
__global__ void conv_xw(const float* __restrict__ x,
                        const float* __restrict__ wq, const float* __restrict__ wk,
                        const float* __restrict__ wv,
                        unsigned short* __restrict__ xb, unsigned short* __restrict__ wqkvb,
                        float2* __restrict__ tab) {
  size_t t = (size_t)blockIdx.x * 256 + threadIdx.x;   // 1,900,544 units
  if (t < (size_t)1048576) {
    size_t e = t * 8;
    float4 a = *(const float4*)(x + e);
    float4 b = *(const float4*)(x + e + 4);
    *(uint4*)(xb + e) = cvt16(a, b);
  } else if (t < (size_t)1835008) {
    size_t e = (t - 1048576) * 8;
    int row = (int)(e >> 11);
    const float* src; size_t off;
    if (row < 2048)       { src = wq; off = e; }
    else if (row < 2560)  { src = wk; off = e - (size_t)2048 * 2048; }
    else                  { src = wv; off = e - (size_t)2560 * 2048; }
    float4 a = *(const float4*)(src + off);
    float4 b = *(const float4*)(src + off + 4);
    *(uint4*)(wqkvb + e) = cvt16(a, b);
  } else {
    int id = (int)(t - 1835008);       // 65536 entries
    int d = id & 31;
    int s = id >> 5;
    float inv = expf((float)d * (-2.0f / 64.0f) * 9.210340371976184f);
    float ang = (float)s * inv;
    float sn, cs;
    sincosf(ang, &sn, &cs);
    tab[id] = make_float2(cs, sn);
  }
}

// ---------------- post-qkv pass: RoPE(q,k) + wo->bf16, one dispatch --------
// units: [0, 655360) rope on q/k; [655360, 1179648) wo conversion.
__global__ void post_qkv(unsigned short* __restrict__ qb,
                         unsigned short* __restrict__ kb,
                         const float* __restrict__ tabf,
                         const float* __restrict__ wo,
                         unsigned short* __restrict__ wob) {
  size_t t = (size_t)blockIdx.x * 256 + threadIdx.x;   // 1,179,648 units
  if (t < (size_t)655360) {
    const float2* tab = (const float2*)tabf;
    int tid = (int)t;
    int oct = tid & 3;
    int head = (tid >> 2) % 40;
    int row = tid / 160;
    int s = row & (SLEN - 1);
    int d0 = oct * 8;
    unsigned short* p = (head < NH)
        ? qb + (size_t)row * QDIM + head * HD
        : kb + (size_t)row * KVDIM + (head - NH) * HD;
    uint4 u0 = *(const uint4*)(p + d0);
    uint4 u1 = *(const uint4*)(p + d0 + 32);
    const unsigned short* a16 = (const unsigned short*)&u0;
    const unsigned short* b16 = (const unsigned short*)&u1;
    unsigned short o0[8], o1[8];
#pragma unroll
    for (int j = 0; j < 8; ++j) {
      float2 cs = tab[s * 32 + d0 + j];
      float a = bf2f(a16[j]), b = bf2f(b16[j]);
      o0[j] = f2bf(a * cs.x - b * cs.y);
      o1[j] = f2bf(b * cs.x + a * cs.y);
    }
    *(uint4*)(p + d0)      = *(const uint4*)o0;
    *(uint4*)(p + d0 + 32) = *(const uint4*)o1;
  } else {
    size_t e = (t - 655360) * 8;
    float4 a = *(const float4*)(wo + e);
    float4 b = *(const float4*)(wo + e + 4);
    *(uint4*)(wob + e) = cvt16(a, b);
  }
}

// ======================= QKV GEMM: 256x192, 8-wave, 2-barrier/tile =========
// Deadline-exact counted vmcnt: end(t) drains only k0(t+1) [vmcnt(8)],
// mid(t) drains only k1(t) [vmcnt(8)] — k1 stays in flight 2x longer than
// the old end-vmcnt(4) scheme. Tail: end(NT-2)=4, mid(NT-1)=0.
__global__ __launch_bounds__(512, 2) void qkv_gemm(
    const unsigned short* __restrict__ Ap, const unsigned short* __restrict__ Bp,
    unsigned short* __restrict__ o_q, unsigned short* __restrict__ o_k,
    unsigned short* __restrict__ o_v)
{
  extern __shared__ unsigned short L[];
  constexpr int NT = 32;             // K = 2048 / 64

  const int bid = blockIdx.x;        // 256 blocks = 16 M x 16 N
  const int swz = (bid & 7) * 32 + (bid >> 3);   // XCD-aware, bijective
  const int bm0 = (swz & 15) * 256;
  const int bn0 = (swz >> 4) * 192;

  const int tid = threadIdx.x;
  const int lane = tid & 63, wid = tid >> 6;
  const int g = lane >> 4, cl = lane & 15;
  const int wm = wid >> 2, wn = wid & 3;

  const int r0 = wid * 32 + (lane >> 2);
  const int s0 = (((lane & 3) ^ ((lane >> 3) & 3)) << 3);
  const unsigned short* gA = Ap + (size_t)(bm0 + r0) * 2048 + s0;
  const unsigned short* gB = Bp + (size_t)(bn0 + r0) * 2048 + s0;  // padded rows ok

  const int slotus = ((g ^ ((cl >> 1) & 3)) << 3);
  const int aread = (wm * 128 + cl) * 32 + slotus;
  const int bread = (wn * 48 + cl) * 32 + slotus;

#define REG_(b, op, kh) ((((b) * 2 + (op)) * 2 + (kh)) * 8192)
#define STG(op, kh, tt, db) do { \
    const unsigned short* s_ = ((op) ? gB : gA) + (tt) * 64 + (kh) * 32; \
    unsigned short* d_ = L + REG_(db, op, kh) + wid * 1024; \
    async16(s_, d_); \
    async16(s_ + 16 * 2048, d_ + 512); \
  } while (0)
#define LDA(dst, kh, mh) \
    _Pragma("unroll") for (int mf = 0; mf < 4; ++mf) \
      dst[mf] = *(const bf16x8*)&L[REG_(cb, 0, kh) + aread + (mh) * 2048 + mf * 512];
#define LDB(dst, kh) \
    _Pragma("unroll") for (int nf = 0; nf < 3; ++nf) \
      dst[nf] = *(const bf16x8*)&L[REG_(cb, 1, kh) + bread + nf * 512];
#define MM(mh, A, B) do { \
    __builtin_amdgcn_s_setprio(1); \
    _Pragma("unroll") for (int mf = 0; mf < 4; ++mf) \
      _Pragma("unroll") for (int nf = 0; nf < 3; ++nf) \
        acc[(mh) * 4 + mf][nf] = __builtin_amdgcn_mfma_f32_16x16x32_bf16( \
            A[mf], B[nf], acc[(mh) * 4 + mf][nf], 0, 0, 0); \
    __builtin_amdgcn_s_setprio(0); \
  } while (0)

  f32x4 acc[8][3] = {};

  // prologue: k0(0),k1(0),k0(1) staged; vmcnt(8) drains exactly k0(0)
  STG(0, 0, 0, 0); STG(1, 0, 0, 0); STG(0, 1, 0, 0); STG(1, 1, 0, 0);
  STG(0, 0, 1, 1); STG(1, 0, 1, 1);
  asm volatile("s_waitcnt vmcnt(8)" ::: "memory");
  __builtin_amdgcn_s_barrier();
  __builtin_amdgcn_sched_barrier(0);

#pragma unroll 1
  for (int t = 0; t < NT; ++t) {
    const int cb = t & 1, nb = cb ^ 1;
    bf16x8 a00[4], a10[4], a01[4], a11[4], b0[3], b1[3];

    if (t + 1 < NT) STG(0, 1, t + 1, nb);
    LDA(a00, 0, 0); LDB(b0, 0);
    if (t + 1 < NT) STG(1, 1, t + 1, nb);
    LDA(a10, 0, 1);
    MM(0, a00, b0);
    LDA(a01, 1, 0); LDB(b1, 1);
    MM(1, a10, b0);
    // mid: drain k1(t) exactly (leave k0(t+1), k1(t+1) in flight)
    if (t + 1 < NT) { asm volatile("s_waitcnt vmcnt(8)" ::: "memory"); }
    else            { asm volatile("s_waitcnt vmcnt(0)" ::: "memory"); }
    asm volatile("s_waitcnt lgkmcnt(0)" ::: "memory");
    __builtin_amdgcn_s_barrier();               // mid: k0(cb) free to overwrite
    __builtin_amdgcn_sched_barrier(0);
    if (t + 2 < NT) STG(0, 0, t + 2, cb);
    LDA(a11, 1, 1);
    MM(0, a01, b1);
    if (t + 2 < NT) STG(1, 0, t + 2, cb);
    MM(1, a11, b1);
    // end: drain k0(t+1) exactly (leave k1(t+1), k0(t+2) in flight)
    if (t + 2 < NT)      { asm volatile("s_waitcnt vmcnt(8)" ::: "memory"); }
    else if (t + 1 < NT) { asm volatile("s_waitcnt vmcnt(4)" ::: "memory"); }
    else                 { asm volatile("s_waitcnt vmcnt(0)" ::: "memory"); }
    asm volatile("s_waitcnt lgkmcnt(0)" ::: "memory");
    __builtin_amdgcn_s_barrier();               // end: tile t+1 published
    __builtin_amdgcn_sched_barrier(0);
  }
#undef MM
#undef LDB
#undef LDA
#undef STG
#undef REG_

  // ---------------- epilogue: direct stores (q / k / v^T) ------------------
  const int rb = bm0 + wm * 128;
#pragma unroll
  for (int m = 0; m < 8; ++m)
#pragma unroll
    for (int nf = 0; nf < 3; ++nf) {
      const int col = bn0 + wn * 48 + nf * 16 + cl;
      if (col < QDIM) {
#pragma unroll
        for (int p = 0; p < 4; ++p) {
          int row = rb + m * 16 + g * 4 + p;
          o_q[(size_t)row * QDIM + col] = f2bf(acc[m][nf][p]);
        }
      } else if (col < QDIM + KVDIM) {
#pragma unroll
        for (int p = 0; p < 4; ++p) {
          int row = rb + m * 16 + g * 4 + p;
          o_k[(size_t)row * KVDIM + col - QDIM] = f2bf(acc[m][nf][p]);
        }
      } else {
        int vc = col - QDIM - KVDIM;            // kvh*64 + d
        int kvh = vc >> 6, d = vc & 63;
        int row0 = rb + m * 16 + g * 4;
        int bb = row0 >> 11, s = row0 & (SLEN - 1);
        unsigned short* dst = o_v + (((size_t)(bb * NKV + kvh) * HD + d) << 11) + s;
        uint2 u;
        u.x = pk2(acc[m][nf][0], acc[m][nf][1]);
        u.y = pk2(acc[m][nf][2], acc[m][nf][3]);
        *(uint2*)dst = u;
      }
    }
}

// ======================= OUT GEMM: 128x256, 8-wave, 2-barrier/tile =========
// Same deadline-exact waits with group size 3: end/mid vmcnt(6); tail 3/0.
__global__ __launch_bounds__(512, 2) void out_gemm(
    const unsigned short* __restrict__ Ap, const unsigned short* __restrict__ Bp,
    float* __restrict__ o_f)
{
  extern __shared__ unsigned short L[];
  constexpr int NT = 32;

  const int bid = blockIdx.x;        // 256 blocks (32 x 8)
  const int swz = (bid & 7) * 32 + (bid >> 3);
  const int bm0 = (swz & 31) * 128;
  const int bn0 = (swz >> 5) * 256;

  const int tid = threadIdx.x;
  const int lane = tid & 63, wid = tid >> 6;
  const int g = lane >> 4, cl = lane & 15;
  const int wm = wid >> 2, wn = wid & 3;

  const int s0 = (((lane & 3) ^ ((lane >> 3) & 3)) << 3);
  const unsigned short* gA = Ap + (size_t)(bm0 + wid * 16 + (lane >> 2)) * 2048 + s0;
  const unsigned short* gB = Bp + (size_t)(bn0 + wid * 32 + (lane >> 2)) * 2048 + s0;

  const int slotus = ((g ^ ((cl >> 1) & 3)) << 3);
  const int aread = (wm * 64 + cl) * 32 + slotus;
  const int bread = (wn * 64 + cl) * 32 + slotus;

#define REGA_(b, kh) ((b) * 24576 + (kh) * 4096)
#define REGB_(b, kh) ((b) * 24576 + 8192 + (kh) * 8192)
#define STGA(kh, tt, db) \
    async16(gA + (tt) * 64 + (kh) * 32, L + REGA_(db, kh) + wid * 512)
#define STGB(kh, tt, db) do { \
    const unsigned short* s_ = gB + (tt) * 64 + (kh) * 32; \
    unsigned short* d_ = L + REGB_(db, kh) + wid * 1024; \
    async16(s_, d_); \
    async16(s_ + 16 * 2048, d_ + 512); \
  } while (0)
#define LA(dst, kh, mp) \
    _Pragma("unroll") for (int mf = 0; mf < 2; ++mf) \
      dst[mf] = *(const bf16x8*)&L[REGA_(cb, kh) + aread + (mp) * 1024 + mf * 512];
#define LB(dst, kh) \
    _Pragma("unroll") for (int nf = 0; nf < 4; ++nf) \
      dst[nf] = *(const bf16x8*)&L[REGB_(cb, kh) + bread + nf * 512];
#define MMO(mp, A, B) do { \
    __builtin_amdgcn_s_setprio(1); \
    _Pragma("unroll") for (int mf = 0; mf < 2; ++mf) \
      _Pragma("unroll") for (int nf = 0; nf < 4; ++nf) \
        acc[(mp) * 2 + mf][nf] = __builtin_amdgcn_mfma_f32_16x16x32_bf16( \
            A[mf], B[nf], acc[(mp) * 2 + mf][nf], 0, 0, 0); \
    __builtin_amdgcn_s_setprio(0); \
  } while (0)

  f32x4 acc[4][4] = {};

  STGA(0, 0, 0); STGB(0, 0, 0); STGA(1, 0, 0); STGB(1, 0, 0);
  STGA(0, 1, 1); STGB(0, 1, 1);
  asm volatile("s_waitcnt vmcnt(6)" ::: "memory");
  __builtin_amdgcn_s_barrier();
  __builtin_amdgcn_sched_barrier(0);

#pragma unroll 1
  for (int t = 0; t < NT; ++t) {
    const int cb = t & 1, nb = cb ^ 1;
    bf16x8 p00[2], p10[2], p01[2], p11[2], b0[4], b1[4];

    if (t + 1 < NT) STGA(1, t + 1, nb);
    LA(p00, 0, 0); LB(b0, 0);
    if (t + 1 < NT) STGB(1, t + 1, nb);
    LA(p10, 0, 1);
    MMO(0, p00, b0);
    LA(p01, 1, 0); LB(b1, 1);
    MMO(1, p10, b0);
    if (t + 1 < NT) { asm volatile("s_waitcnt vmcnt(6)" ::: "memory"); }
    else            { asm volatile("s_waitcnt vmcnt(0)" ::: "memory"); }
    asm volatile("s_waitcnt lgkmcnt(0)" ::: "memory");
    __builtin_amdgcn_s_barrier();
    __builtin_amdgcn_sched_barrier(0);
    if (t + 2 < NT) STGA(0, t + 2, cb);
    LA(p11, 1, 1);
    MMO(0, p01, b1);
    if (t + 2 < NT) STGB(0, t + 2, cb);
    MMO(1, p11, b1);
    if (t + 2 < NT)      { asm volatile("s_waitcnt vmcnt(6)" ::: "memory"); }
    else if (t + 1 < NT) { asm volatile("s_waitcnt vmcnt(3)" ::: "memory"); }
    else                 { asm volatile("s_waitcnt vmcnt(0)" ::: "memory"); }
    asm volatile("s_waitcnt lgkmcnt(0)" ::: "memory");
    __builtin_amdgcn_s_barrier();
    __builtin_amdgcn_sched_barrier(0);
  }
#undef MMO
#undef LB
#undef LA
#undef STGB
#undef STGA
#undef REGB_
#undef REGA_

  const int rb = bm0 + wm * 64;
  const int colb = bn0 + wn * 64;
#pragma unroll
  for (int m = 0; m < 4; ++m)
#pragma unroll
    for (int nf = 0; nf < 4; ++nf)
#pragma unroll
      for (int p = 0; p < 4; ++p) {
        int row = rb + m * 16 + g * 4 + p;
        o_f[(size_t)row * 2048 + colb + nf * 16 + cl] = acc[m][nf][p];
      }
}

// ---------------- Flash attention: 32 q/wave, K and V both prefetched ------
__global__ __launch_bounds__(256) void attn(
    const unsigned short* __restrict__ qb, const unsigned short* __restrict__ kb,
    const unsigned short* __restrict__ vt, unsigned short* __restrict__ ao)
{
  __shared__ __align__(16) unsigned short Plds[4][2][16][40];
  const int lane = threadIdx.x & 63, wid = threadIdx.x >> 6;
  const int g = lane >> 4, cl = lane & 15;
  const int qt = blockIdx.x * 4 + wid;         // 0..4095 tiles of 32 queries
  const int bh = qt >> 6, tl = qt & 63;
  const int i0 = tl * 32;
  const int b = bh >> 5, h = bh & 31, kvh = (bh & 31) >> 2;
  const int qi0 = i0 + cl, qi1 = i0 + 16 + cl;

  const unsigned short* qp0 = qb + ((size_t)(b * SLEN + qi0) * NH + h) * HD + g * 8;
  const unsigned short* qp1 = qb + ((size_t)(b * SLEN + qi1) * NH + h) * HD + g * 8;
  bf16x8 qf00 = *(const bf16x8*)qp0, qf01 = *(const bf16x8*)(qp0 + 32);
  bf16x8 qf10 = *(const bf16x8*)qp1, qf11 = *(const bf16x8*)(qp1 + 32);

  const unsigned short* kbase = kb + ((size_t)b * SLEN * NKV + kvh) * HD + g * 8;
  const unsigned short* vbase = vt + ((size_t)(b * NKV + kvh) * HD) * SLEN;

  f32x4 acc0[4] = {}, acc1[4] = {};
  float m0 = -1e30f, l0 = 0.f, m1 = -1e30f, l1 = 0.f;
  const int jb = (i0 > WINH) ? (i0 - WINH) : 0;

#define LOADK(dst, jj) do { \
    _Pragma("unroll") for (int t = 0; t < 2; ++t) { \
      int krow = (jj) + 16 * t + cl; \
      if (krow > SLEN - 1) krow = SLEN - 1; \
      const unsigned short* kp_ = kbase + (size_t)krow * KVDIM; \
      dst[t * 2]     = *(const bf16x8*)kp_; \
      dst[t * 2 + 1] = *(const bf16x8*)(kp_ + 32); \
    } \
  } while (0)

#define LOADV(dst, jj) do { \
    int jv = (jj) + g * 8; \
    if (jv > SLEN - 8) jv = SLEN - 8; \
    _Pragma("unroll") for (int vb2 = 0; vb2 < 4; ++vb2) \
      dst[vb2] = *(const bf16x8*)(vbase + (size_t)(vb2 * 16 + cl) * SLEN + jv); \
  } while (0)

#define SOFTMAX(SAC, MR, LR, ACC, QI, QF) do { \
    float sm[2][4]; float mx = -1e30f; \
    _Pragma("unroll") for (int t = 0; t < 2; ++t) \
      _Pragma("unroll") for (int p = 0; p < 4; ++p) { \
        int kj = j0 + 16 * t + 4 * g + p; \
        bool ok = (kj <= (QI)) && ((QI) - kj <= WINH); \
        float v = ok ? SAC[t][p] * 0.125f : -1e30f; \
        sm[t][p] = v; mx = fmaxf(mx, v); \
      } \
    mx = fmaxf(mx, __shfl_xor(mx, 16)); \
    mx = fmaxf(mx, __shfl_xor(mx, 32)); \
    float mnew = fmaxf(MR, mx); \
    float corr = __expf(MR - mnew); \
    float ps = 0.f; unsigned pw00, pw01, pw10, pw11; \
    { \
      float p0 = __expf(sm[0][0] - mnew), p1 = __expf(sm[0][1] - mnew); \
      float p2 = __expf(sm[0][2] - mnew), p3 = __expf(sm[0][3] - mnew); \
      ps += p0 + p1 + p2 + p3; pw00 = cvtpk(p0, p1); pw01 = cvtpk(p2, p3); \
      float p4 = __expf(sm[1][0] - mnew), p5 = __expf(sm[1][1] - mnew); \
      float p6 = __expf(sm[1][2] - mnew), p7 = __expf(sm[1][3] - mnew); \
      ps += p4 + p5 + p6 + p7; pw10 = cvtpk(p4, p5); pw11 = cvtpk(p6, p7); \
    } \
    ps += __shfl_xor(ps, 16); ps += __shfl_xor(ps, 32); \
    LR = LR * corr + ps; MR = mnew; \
    _Pragma("unroll") for (int vb2 = 0; vb2 < 4; ++vb2) \
      _Pragma("unroll") for (int p = 0; p < 4; ++p) ACC[vb2][p] *= corr; \
    *(unsigned*)&Plds[wid][QF][cl][4 * g]          = pw00; \
    *(unsigned*)&Plds[wid][QF][cl][4 * g + 2]      = pw01; \
    *(unsigned*)&Plds[wid][QF][cl][16 + 4 * g]     = pw10; \
    *(unsigned*)&Plds[wid][QF][cl][16 + 4 * g + 2] = pw11; \
  } while (0)

#define BODY(KC, KN, VC, VN) do { \
    LOADK(KN, j0 + 32);                          /* prefetch next K tile */ \
    LOADV(VN, j0 + 32);                          /* prefetch next V tile */ \
    f32x4 s0[2], s1[2]; \
    _Pragma("unroll") for (int t = 0; t < 2; ++t) { \
      f32x4 z = {}; \
      z = __builtin_amdgcn_mfma_f32_16x16x32_bf16(KC[t * 2], qf00, z, 0, 0, 0); \
      z = __builtin_amdgcn_mfma_f32_16x16x32_bf16(KC[t * 2 + 1], qf01, z, 0, 0, 0); \
      s0[t] = z; \
      f32x4 z2 = {}; \
      z2 = __builtin_amdgcn_mfma_f32_16x16x32_bf16(KC[t * 2], qf10, z2, 0, 0, 0); \
      z2 = __builtin_amdgcn_mfma_f32_16x16x32_bf16(KC[t * 2 + 1], qf11, z2, 0, 0, 0); \
      s1[t] = z2; \
    } \
    SOFTMAX(s0, m0, l0, acc0, qi0, 0); \
    SOFTMAX(s1, m1, l1, acc1, qi1, 1); \
    bf16x8 pf0 = *(const bf16x8*)&Plds[wid][0][cl][g * 8]; \
    bf16x8 pf1 = *(const bf16x8*)&Plds[wid][1][cl][g * 8]; \
    _Pragma("unroll") for (int vb2 = 0; vb2 < 4; ++vb2) \
      acc0[vb2] = __builtin_amdgcn_mfma_f32_16x16x32_bf16(VC[vb2], pf0, acc0[vb2], 0, 0, 0); \
    _Pragma("unroll") for (int vb2 = 0; vb2 < 4; ++vb2) \
      acc1[vb2] = __builtin_amdgcn_mfma_f32_16x16x32_bf16(VC[vb2], pf1, acc1[vb2], 0, 0, 0); \
  } while (0)

  bf16x8 kA[4], kB[4], vA[4], vB[4];
  LOADK(kA, jb); LOADV(vA, jb);
  int j0 = jb;
  for (;;) {
    BODY(kA, kB, vA, vB); j0 += 32; if (j0 > i0) break;
    BODY(kB, kA, vB, vA); j0 += 32; if (j0 > i0) break;
  }
#undef BODY
#undef SOFTMAX
#undef LOADV
#undef LOADK

  float inv0 = 1.0f / l0, inv1 = 1.0f / l1;
  unsigned short* op0 = ao + ((size_t)(b * SLEN + qi0) * NH + h) * HD;
  unsigned short* op1 = ao + ((size_t)(b * SLEN + qi1) * NH + h) * HD;
#pragma unroll
  for (int vbk = 0; vbk < 4; ++vbk) {
    *(unsigned*)(op0 + vbk * 16 + g * 4)     = cvtpk(acc0[vbk][0] * inv0, acc0[vbk][1] * inv0);
    *(unsigned*)(op0 + vbk * 16 + g * 4 + 2) = cvtpk(acc0[vbk][2] * inv0, acc0[vbk][3] * inv0);
    *(unsigned*)(op1 + vbk * 16 + g * 4)     = cvtpk(acc1[vbk][0] * inv1, acc1[vbk][1] * inv1);
    *(unsigned*)(op1 + vbk * 16 + g * 4 + 2) = cvtpk(acc1[vbk][2] * inv1, acc1[vbk][3] * inv1);
  }
}

// ---------------- launch ---------------------------------------------------
extern "C" void kernel_launch(void* const* d_in, const int* in_sizes, int n_in,
                              void* d_out, int out_size, void* d_ws, size_t ws_size,
                              hipStream_t stream) {
  const float* x  = (const float*)d_in[0];
  const float* wq = (const float*)d_in[1];
  const float* wk = (const float*)d_in[2];
  const float* wv = (const float*)d_in[3];
  const float* wo = (const float*)d_in[4];
  float* out = (float*)d_out;

  char* w = (char*)d_ws;
  unsigned short* wqkvb = (unsigned short*)w; w += (size_t)3136 * 2048 * 2;   // +64 pad rows
  unsigned short* xb    = (unsigned short*)w; w += (size_t)MROWS * QDIM * 2;  // 16 MB
  unsigned short* qb    = (unsigned short*)w; w += (size_t)MROWS * QDIM * 2;  // 16 MB
  unsigned short* kb    = (unsigned short*)w; w += (size_t)MROWS * KVDIM * 2; // 4 MB
  unsigned short* vt    = (unsigned short*)w; w += (size_t)MROWS * KVDIM * 2; // 4 MB
  float* tab            = (float*)w;          w += (size_t)SLEN * 32 * 8;     // 0.5 MB
  // aliases (lifetimes disjoint in stream order):
  unsigned short* wob = wqkvb;   // wo bf16 — written after qkv_gemm reads wqkvb
  unsigned short* ao  = xb;      // attn output — written after qkv_gemm reads xb

  hipFuncSetAttribute((const void*)qkv_gemm,
                      hipFuncAttributeMaxDynamicSharedMemorySize, 131072);
  hipFuncSetAttribute((const void*)out_gemm,
                      hipFuncAttributeMaxDynamicSharedMemorySize, 98304);

  conv_xw<<<7424, 256, 0, stream>>>(x, wq, wk, wv, xb, wqkvb, (float2*)tab);
  qkv_gemm<<<256, 512, 131072, stream>>>(xb, wqkvb, qb, kb, vt);
  post_qkv<<<4608, 256, 0, stream>>>(qb, kb, tab, wo, wob);
  attn<<<(NB * NH * (SLEN / 32)) / 4, 256, 0, stream>>>(qb, kb, vt, ao);
  out_gemm<<<256, 512, 98304, stream>>>(ao, wob, out);
}

// Round 18
// 160.601 us; speedup vs baseline: 1.0003x; 1.0003x over previous
//
#include <hip/hip_runtime.h>
#include <cstdint>
#include <cstddef>

#define SLEN 2048
#define NB 2
#define NH 32
#define NKV 8
#define HD 64
#define MROWS 4096   // NB*SLEN
#define QDIM 2048    // NH*HD
#define KVDIM 512    // NKV*HD
#define WINH 256     // WIN/2

typedef float f32x4 __attribute__((ext_vector_type(4)));
typedef __bf16 bf16x8 __attribute__((ext_vector_type(8)));

__device__ __forceinline__ unsigned short f2bf(float f) {
  union { float f; unsigned u; } v; v.f = f;
  unsigned r = v.u + 0x7fffu + ((v.u >> 16) & 1u);
  return (unsigned short)(r >> 16);
}
__device__ __forceinline__ float bf2f(unsigned short h) {
  union { unsigned u; float f; } v; v.u = ((unsigned)h) << 16;
  return v.f;
}
__device__ __forceinline__ unsigned pk2(float a, float b) {
  return (unsigned)f2bf(a) | ((unsigned)f2bf(b) << 16);
}
// HW packed fp32->bf16 (RNE), 1 inst per pair
__device__ __forceinline__ unsigned cvtpk(float a, float b) {
  unsigned r;
  asm("v_cvt_pk_bf16_f32 %0, %1, %2" : "=v"(r) : "v"(a), "v"(b));
  return r;
}
__device__ __forceinline__ uint4 cvt16(float4 a, float4 b) {
  uint4 u;
  u.x = pk2(a.x, a.y); u.y = pk2(a.z, a.w);
  u.z = pk2(b.x, b.y); u.w = pk2(b.z, b.w);
  return u;
}
// async global->LDS, 16B per lane; LDS dest is wave-uniform base + lane*16
__device__ __forceinline__ void async16(const unsigned short* g, unsigned short* l) {
  __builtin_amdgcn_global_load_lds(
      (const __attribute__((address_space(1))) unsigned int*)g,
      (__attribute__((address_space(3))) unsigned int*)l, 16, 0, 0);
}

// ---------------- merged conversions + RoPE table --------------------------
// units: [0,1048576) x->xb (x8), [.., 1835008) wqkv->wqkvb (x8),
// [.., 1900544) rope table entries.
__global__ void conv_xw(const float* __restrict__ x,
                        const float* __restrict__ wq, const float* __restrict__ wk,
                        const float* __restrict__ wv,
                        unsigned short* __restrict__ xb, unsigned short* __restrict__ wqkvb,
                        float2* __restrict__ tab) {
  size_t t = (size_t)blockIdx.x * 256 + threadIdx.x;   // 1,900,544 units
  if (t < (size_t)1048576) {
    size_t e = t * 8;
    float4 a = *(const float4*)(x + e);
    float4 b = *(const float4*)(x + e + 4);
    *(uint4*)(xb + e) = cvt16(a, b);
  } else if (t < (size_t)1835008) {
    size_t e = (t - 1048576) * 8;
    int row = (int)(e >> 11);
    const float* src; size_t off;
    if (row < 2048)       { src = wq; off = e; }
    else if (row < 2560)  { src = wk; off = e - (size_t)2048 * 2048; }
    else                  { src = wv; off = e - (size_t)2560 * 2048; }
    float4 a = *(const float4*)(src + off);
    float4 b = *(const float4*)(src + off + 4);
    *(uint4*)(wqkvb + e) = cvt16(a, b);
  } else {
    int id = (int)(t - 1835008);       // 65536 entries
    int d = id & 31;
    int s = id >> 5;
    float inv = expf((float)d * (-2.0f / 64.0f) * 9.210340371976184f);
    float ang = (float)s * inv;
    float sn, cs;
    sincosf(ang, &sn, &cs);
    tab[id] = make_float2(cs, sn);
  }
}

// ---------------- post-qkv pass: RoPE(q,k) + wo->bf16, one dispatch --------
// units: [0, 655360) rope on q/k; [655360, 1179648) wo conversion.
__global__ void post_qkv(unsigned short* __restrict__ qb,
                         unsigned short* __restrict__ kb,
                         const float* __restrict__ tabf,
                         const float* __restrict__ wo,
                         unsigned short* __restrict__ wob) {
  size_t t = (size_t)blockIdx.x * 256 + threadIdx.x;   // 1,179,648 units
  if (t < (size_t)655360) {
    const float2* tab = (const float2*)tabf;
    int tid = (int)t;
    int oct = tid & 3;
    int head = (tid >> 2) % 40;
    int row = tid / 160;
    int s = row & (SLEN - 1);
    int d0 = oct * 8;
    unsigned short* p = (head < NH)
        ? qb + (size_t)row * QDIM + head * HD
        : kb + (size_t)row * KVDIM + (head - NH) * HD;
    uint4 u0 = *(const uint4*)(p + d0);
    uint4 u1 = *(const uint4*)(p + d0 + 32);
    const unsigned short* a16 = (const unsigned short*)&u0;
    const unsigned short* b16 = (const unsigned short*)&u1;
    unsigned short o0[8], o1[8];
#pragma unroll
    for (int j = 0; j < 8; ++j) {
      float2 cs = tab[s * 32 + d0 + j];
      float a = bf2f(a16[j]), b = bf2f(b16[j]);
      o0[j] = f2bf(a * cs.x - b * cs.y);
      o1[j] = f2bf(b * cs.x + a * cs.y);
    }
    *(uint4*)(p + d0)      = *(const uint4*)o0;
    *(uint4*)(p + d0 + 32) = *(const uint4*)o1;
  } else {
    size_t e = (t - 655360) * 8;
    float4 a = *(const float4*)(wo + e);
    float4 b = *(const float4*)(wo + e + 4);
    *(uint4*)(wob + e) = cvt16(a, b);
  }
}

// ======================= QKV GEMM: 256x192, 8-wave, 2-barrier/tile =========
// NOTE: end-of-tile vmcnt(4) is CORRECT and deadline-exact: kh1 ds_reads
// (a01/b1) are register-pipelined BEFORE the mid barrier, so k1(t) must be
// resident by end(t-1). R17's vmcnt(8) raced exactly here (absmax 0.058).
__global__ __launch_bounds__(512, 2) void qkv_gemm(
    const unsigned short* __restrict__ Ap, const unsigned short* __restrict__ Bp,
    unsigned short* __restrict__ o_q, unsigned short* __restrict__ o_k,
    unsigned short* __restrict__ o_v)
{
  extern __shared__ unsigned short L[];
  constexpr int NT = 32;             // K = 2048 / 64

  const int bid = blockIdx.x;        // 256 blocks = 16 M x 16 N
  const int swz = (bid & 7) * 32 + (bid >> 3);   // XCD-aware, bijective
  const int bm0 = (swz & 15) * 256;
  const int bn0 = (swz >> 4) * 192;

  const int tid = threadIdx.x;
  const int lane = tid & 63, wid = tid >> 6;
  const int g = lane >> 4, cl = lane & 15;
  const int wm = wid >> 2, wn = wid & 3;

  const int r0 = wid * 32 + (lane >> 2);
  const int s0 = (((lane & 3) ^ ((lane >> 3) & 3)) << 3);
  const unsigned short* gA = Ap + (size_t)(bm0 + r0) * 2048 + s0;
  const unsigned short* gB = Bp + (size_t)(bn0 + r0) * 2048 + s0;  // padded rows ok

  const int slotus = ((g ^ ((cl >> 1) & 3)) << 3);
  const int aread = (wm * 128 + cl) * 32 + slotus;
  const int bread = (wn * 48 + cl) * 32 + slotus;

#define REG_(b, op, kh) ((((b) * 2 + (op)) * 2 + (kh)) * 8192)
#define STG(op, kh, tt, db) do { \
    const unsigned short* s_ = ((op) ? gB : gA) + (tt) * 64 + (kh) * 32; \
    unsigned short* d_ = L + REG_(db, op, kh) + wid * 1024; \
    async16(s_, d_); \
    async16(s_ + 16 * 2048, d_ + 512); \
  } while (0)
#define LDA(dst, kh, mh) \
    _Pragma("unroll") for (int mf = 0; mf < 4; ++mf) \
      dst[mf] = *(const bf16x8*)&L[REG_(cb, 0, kh) + aread + (mh) * 2048 + mf * 512];
#define LDB(dst, kh) \
    _Pragma("unroll") for (int nf = 0; nf < 3; ++nf) \
      dst[nf] = *(const bf16x8*)&L[REG_(cb, 1, kh) + bread + nf * 512];
#define MM(mh, A, B) do { \
    __builtin_amdgcn_s_setprio(1); \
    _Pragma("unroll") for (int mf = 0; mf < 4; ++mf) \
      _Pragma("unroll") for (int nf = 0; nf < 3; ++nf) \
        acc[(mh) * 4 + mf][nf] = __builtin_amdgcn_mfma_f32_16x16x32_bf16( \
            A[mf], B[nf], acc[(mh) * 4 + mf][nf], 0, 0, 0); \
    __builtin_amdgcn_s_setprio(0); \
  } while (0)

  f32x4 acc[8][3] = {};

  STG(0, 0, 0, 0); STG(1, 0, 0, 0); STG(0, 1, 0, 0); STG(1, 1, 0, 0);
  STG(0, 0, 1, 1); STG(1, 0, 1, 1);
  asm volatile("s_waitcnt vmcnt(4)" ::: "memory");
  __builtin_amdgcn_s_barrier();
  __builtin_amdgcn_sched_barrier(0);

#pragma unroll 1
  for (int t = 0; t < NT; ++t) {
    const int cb = t & 1, nb = cb ^ 1;
    bf16x8 a00[4], a10[4], a01[4], a11[4], b0[3], b1[3];

    if (t + 1 < NT) STG(0, 1, t + 1, nb);
    LDA(a00, 0, 0); LDB(b0, 0);
    if (t + 1 < NT) STG(1, 1, t + 1, nb);
    LDA(a10, 0, 1);
    MM(0, a00, b0);
    LDA(a01, 1, 0); LDB(b1, 1);
    MM(1, a10, b0);
    asm volatile("s_waitcnt lgkmcnt(0)" ::: "memory");
    __builtin_amdgcn_s_barrier();               // mid: k0(cb) free to overwrite
    __builtin_amdgcn_sched_barrier(0);
    if (t + 2 < NT) STG(0, 0, t + 2, cb);
    LDA(a11, 1, 1);
    MM(0, a01, b1);
    if (t + 2 < NT) STG(1, 0, t + 2, cb);
    MM(1, a11, b1);
    if (t + 2 < NT) { asm volatile("s_waitcnt vmcnt(4)" ::: "memory"); }
    else            { asm volatile("s_waitcnt vmcnt(0)" ::: "memory"); }
    asm volatile("s_waitcnt lgkmcnt(0)" ::: "memory");
    __builtin_amdgcn_s_barrier();               // end: tile t+1 published
    __builtin_amdgcn_sched_barrier(0);
  }
#undef MM
#undef LDB
#undef LDA
#undef STG
#undef REG_

  // ---------------- epilogue: direct stores (q / k / v^T) ------------------
  const int rb = bm0 + wm * 128;
#pragma unroll
  for (int m = 0; m < 8; ++m)
#pragma unroll
    for (int nf = 0; nf < 3; ++nf) {
      const int col = bn0 + wn * 48 + nf * 16 + cl;
      if (col < QDIM) {
#pragma unroll
        for (int p = 0; p < 4; ++p) {
          int row = rb + m * 16 + g * 4 + p;
          o_q[(size_t)row * QDIM + col] = f2bf(acc[m][nf][p]);
        }
      } else if (col < QDIM + KVDIM) {
#pragma unroll
        for (int p = 0; p < 4; ++p) {
          int row = rb + m * 16 + g * 4 + p;
          o_k[(size_t)row * KVDIM + col - QDIM] = f2bf(acc[m][nf][p]);
        }
      } else {
        int vc = col - QDIM - KVDIM;            // kvh*64 + d
        int kvh = vc >> 6, d = vc & 63;
        int row0 = rb + m * 16 + g * 4;
        int bb = row0 >> 11, s = row0 & (SLEN - 1);
        unsigned short* dst = o_v + (((size_t)(bb * NKV + kvh) * HD + d) << 11) + s;
        uint2 u;
        u.x = pk2(acc[m][nf][0], acc[m][nf][1]);
        u.y = pk2(acc[m][nf][2], acc[m][nf][3]);
        *(uint2*)dst = u;
      }
    }
}

// ======================= OUT GEMM: 128x256, 8-wave, 2-barrier/tile =========
__global__ __launch_bounds__(512, 2) void out_gemm(
    const unsigned short* __restrict__ Ap, const unsigned short* __restrict__ Bp,
    float* __restrict__ o_f)
{
  extern __shared__ unsigned short L[];
  constexpr int NT = 32;

  const int bid = blockIdx.x;        // 256 blocks (32 x 8)
  const int swz = (bid & 7) * 32 + (bid >> 3);
  const int bm0 = (swz & 31) * 128;
  const int bn0 = (swz >> 5) * 256;

  const int tid = threadIdx.x;
  const int lane = tid & 63, wid = tid >> 6;
  const int g = lane >> 4, cl = lane & 15;
  const int wm = wid >> 2, wn = wid & 3;

  const int s0 = (((lane & 3) ^ ((lane >> 3) & 3)) << 3);
  const unsigned short* gA = Ap + (size_t)(bm0 + wid * 16 + (lane >> 2)) * 2048 + s0;
  const unsigned short* gB = Bp + (size_t)(bn0 + wid * 32 + (lane >> 2)) * 2048 + s0;

  const int slotus = ((g ^ ((cl >> 1) & 3)) << 3);
  const int aread = (wm * 64 + cl) * 32 + slotus;
  const int bread = (wn * 64 + cl) * 32 + slotus;

#define REGA_(b, kh) ((b) * 24576 + (kh) * 4096)
#define REGB_(b, kh) ((b) * 24576 + 8192 + (kh) * 8192)
#define STGA(kh, tt, db) \
    async16(gA + (tt) * 64 + (kh) * 32, L + REGA_(db, kh) + wid * 512)
#define STGB(kh, tt, db) do { \
    const unsigned short* s_ = gB + (tt) * 64 + (kh) * 32; \
    unsigned short* d_ = L + REGB_(db, kh) + wid * 1024; \
    async16(s_, d_); \
    async16(s_ + 16 * 2048, d_ + 512); \
  } while (0)
#define LA(dst, kh, mp) \
    _Pragma("unroll") for (int mf = 0; mf < 2; ++mf) \
      dst[mf] = *(const bf16x8*)&L[REGA_(cb, kh) + aread + (mp) * 1024 + mf * 512];
#define LB(dst, kh) \
    _Pragma("unroll") for (int nf = 0; nf < 4; ++nf) \
      dst[nf] = *(const bf16x8*)&L[REGB_(cb, kh) + bread + nf * 512];
#define MMO(mp, A, B) do { \
    __builtin_amdgcn_s_setprio(1); \
    _Pragma("unroll") for (int mf = 0; mf < 2; ++mf) \
      _Pragma("unroll") for (int nf = 0; nf < 4; ++nf) \
        acc[(mp) * 2 + mf][nf] = __builtin_amdgcn_mfma_f32_16x16x32_bf16( \
            A[mf], B[nf], acc[(mp) * 2 + mf][nf], 0, 0, 0); \
    __builtin_amdgcn_s_setprio(0); \
  } while (0)

  f32x4 acc[4][4] = {};

  STGA(0, 0, 0); STGB(0, 0, 0); STGA(1, 0, 0); STGB(1, 0, 0);
  STGA(0, 1, 1); STGB(0, 1, 1);
  asm volatile("s_waitcnt vmcnt(3)" ::: "memory");
  __builtin_amdgcn_s_barrier();
  __builtin_amdgcn_sched_barrier(0);

#pragma unroll 1
  for (int t = 0; t < NT; ++t) {
    const int cb = t & 1, nb = cb ^ 1;
    bf16x8 p00[2], p10[2], p01[2], p11[2], b0[4], b1[4];

    if (t + 1 < NT) STGA(1, t + 1, nb);
    LA(p00, 0, 0); LB(b0, 0);
    if (t + 1 < NT) STGB(1, t + 1, nb);
    LA(p10, 0, 1);
    MMO(0, p00, b0);
    LA(p01, 1, 0); LB(b1, 1);
    MMO(1, p10, b0);
    asm volatile("s_waitcnt lgkmcnt(0)" ::: "memory");
    __builtin_amdgcn_s_barrier();
    __builtin_amdgcn_sched_barrier(0);
    if (t + 2 < NT) STGA(0, t + 2, cb);
    LA(p11, 1, 1);
    MMO(0, p01, b1);
    if (t + 2 < NT) STGB(0, t + 2, cb);
    MMO(1, p11, b1);
    if (t + 2 < NT) { asm volatile("s_waitcnt vmcnt(3)" ::: "memory"); }
    else            { asm volatile("s_waitcnt vmcnt(0)" ::: "memory"); }
    asm volatile("s_waitcnt lgkmcnt(0)" ::: "memory");
    __builtin_amdgcn_s_barrier();
    __builtin_amdgcn_sched_barrier(0);
  }
#undef MMO
#undef LB
#undef LA
#undef STGB
#undef STGA
#undef REGB_
#undef REGA_

  const int rb = bm0 + wm * 64;
  const int colb = bn0 + wn * 64;
#pragma unroll
  for (int m = 0; m < 4; ++m)
#pragma unroll
    for (int nf = 0; nf < 4; ++nf)
#pragma unroll
      for (int p = 0; p < 4; ++p) {
        int row = rb + m * 16 + g * 4 + p;
        o_f[(size_t)row * 2048 + colb + nf * 16 + cl] = acc[m][nf][p];
      }
}

// ---------------- Flash attention: 32 q/wave, K and V both prefetched ------
__global__ __launch_bounds__(256) void attn(
    const unsigned short* __restrict__ qb, const unsigned short* __restrict__ kb,
    const unsigned short* __restrict__ vt, unsigned short* __restrict__ ao)
{
  __shared__ __align__(16) unsigned short Plds[4][2][16][40];
  const int lane = threadIdx.x & 63, wid = threadIdx.x >> 6;
  const int g = lane >> 4, cl = lane & 15;
  const int qt = blockIdx.x * 4 + wid;         // 0..4095 tiles of 32 queries
  const int bh = qt >> 6, tl = qt & 63;
  const int i0 = tl * 32;
  const int b = bh >> 5, h = bh & 31, kvh = (bh & 31) >> 2;
  const int qi0 = i0 + cl, qi1 = i0 + 16 + cl;

  const unsigned short* qp0 = qb + ((size_t)(b * SLEN + qi0) * NH + h) * HD + g * 8;
  const unsigned short* qp1 = qb + ((size_t)(b * SLEN + qi1) * NH + h) * HD + g * 8;
  bf16x8 qf00 = *(const bf16x8*)qp0, qf01 = *(const bf16x8*)(qp0 + 32);
  bf16x8 qf10 = *(const bf16x8*)qp1, qf11 = *(const bf16x8*)(qp1 + 32);

  const unsigned short* kbase = kb + ((size_t)b * SLEN * NKV + kvh) * HD + g * 8;
  const unsigned short* vbase = vt + ((size_t)(b * NKV + kvh) * HD) * SLEN;

  f32x4 acc0[4] = {}, acc1[4] = {};
  float m0 = -1e30f, l0 = 0.f, m1 = -1e30f, l1 = 0.f;
  const int jb = (i0 > WINH) ? (i0 - WINH) : 0;

#define LOADK(dst, jj) do { \
    _Pragma("unroll") for (int t = 0; t < 2; ++t) { \
      int krow = (jj) + 16 * t + cl; \
      if (krow > SLEN - 1) krow = SLEN - 1; \
      const unsigned short* kp_ = kbase + (size_t)krow * KVDIM; \
      dst[t * 2]     = *(const bf16x8*)kp_; \
      dst[t * 2 + 1] = *(const bf16x8*)(kp_ + 32); \
    } \
  } while (0)

#define LOADV(dst, jj) do { \
    int jv = (jj) + g * 8; \
    if (jv > SLEN - 8) jv = SLEN - 8; \
    _Pragma("unroll") for (int vb2 = 0; vb2 < 4; ++vb2) \
      dst[vb2] = *(const bf16x8*)(vbase + (size_t)(vb2 * 16 + cl) * SLEN + jv); \
  } while (0)

#define SOFTMAX(SAC, MR, LR, ACC, QI, QF) do { \
    float sm[2][4]; float mx = -1e30f; \
    _Pragma("unroll") for (int t = 0; t < 2; ++t) \
      _Pragma("unroll") for (int p = 0; p < 4; ++p) { \
        int kj = j0 + 16 * t + 4 * g + p; \
        bool ok = (kj <= (QI)) && ((QI) - kj <= WINH); \
        float v = ok ? SAC[t][p] * 0.125f : -1e30f; \
        sm[t][p] = v; mx = fmaxf(mx, v); \
      } \
    mx = fmaxf(mx, __shfl_xor(mx, 16)); \
    mx = fmaxf(mx, __shfl_xor(mx, 32)); \
    float mnew = fmaxf(MR, mx); \
    float corr = __expf(MR - mnew); \
    float ps = 0.f; unsigned pw00, pw01, pw10, pw11; \
    { \
      float p0 = __expf(sm[0][0] - mnew), p1 = __expf(sm[0][1] - mnew); \
      float p2 = __expf(sm[0][2] - mnew), p3 = __expf(sm[0][3] - mnew); \
      ps += p0 + p1 + p2 + p3; pw00 = cvtpk(p0, p1); pw01 = cvtpk(p2, p3); \
      float p4 = __expf(sm[1][0] - mnew), p5 = __expf(sm[1][1] - mnew); \
      float p6 = __expf(sm[1][2] - mnew), p7 = __expf(sm[1][3] - mnew); \
      ps += p4 + p5 + p6 + p7; pw10 = cvtpk(p4, p5); pw11 = cvtpk(p6, p7); \
    } \
    ps += __shfl_xor(ps, 16); ps += __shfl_xor(ps, 32); \
    LR = LR * corr + ps; MR = mnew; \
    _Pragma("unroll") for (int vb2 = 0; vb2 < 4; ++vb2) \
      _Pragma("unroll") for (int p = 0; p < 4; ++p) ACC[vb2][p] *= corr; \
    *(unsigned*)&Plds[wid][QF][cl][4 * g]          = pw00; \
    *(unsigned*)&Plds[wid][QF][cl][4 * g + 2]      = pw01; \
    *(unsigned*)&Plds[wid][QF][cl][16 + 4 * g]     = pw10; \
    *(unsigned*)&Plds[wid][QF][cl][16 + 4 * g + 2] = pw11; \
  } while (0)

#define BODY(KC, KN, VC, VN) do { \
    LOADK(KN, j0 + 32);                          /* prefetch next K tile */ \
    LOADV(VN, j0 + 32);                          /* prefetch next V tile */ \
    f32x4 s0[2], s1[2]; \
    _Pragma("unroll") for (int t = 0; t < 2; ++t) { \
      f32x4 z = {}; \
      z = __builtin_amdgcn_mfma_f32_16x16x32_bf16(KC[t * 2], qf00, z, 0, 0, 0); \
      z = __builtin_amdgcn_mfma_f32_16x16x32_bf16(KC[t * 2 + 1], qf01, z, 0, 0, 0); \
      s0[t] = z; \
      f32x4 z2 = {}; \
      z2 = __builtin_amdgcn_mfma_f32_16x16x32_bf16(KC[t * 2], qf10, z2, 0, 0, 0); \
      z2 = __builtin_amdgcn_mfma_f32_16x16x32_bf16(KC[t * 2 + 1], qf11, z2, 0, 0, 0); \
      s1[t] = z2; \
    } \
    SOFTMAX(s0, m0, l0, acc0, qi0, 0); \
    SOFTMAX(s1, m1, l1, acc1, qi1, 1); \
    bf16x8 pf0 = *(const bf16x8*)&Plds[wid][0][cl][g * 8]; \
    bf16x8 pf1 = *(const bf16x8*)&Plds[wid][1][cl][g * 8]; \
    _Pragma("unroll") for (int vb2 = 0; vb2 < 4; ++vb2) \
      acc0[vb2] = __builtin_amdgcn_mfma_f32_16x16x32_bf16(VC[vb2], pf0, acc0[vb2], 0, 0, 0); \
    _Pragma("unroll") for (int vb2 = 0; vb2 < 4; ++vb2) \
      acc1[vb2] = __builtin_amdgcn_mfma_f32_16x16x32_bf16(VC[vb2], pf1, acc1[vb2], 0, 0, 0); \
  } while (0)

  bf16x8 kA[4], kB[4], vA[4], vB[4];
  LOADK(kA, jb); LOADV(vA, jb);
  int j0 = jb;
  for (;;) {
    BODY(kA, kB, vA, vB); j0 += 32; if (j0 > i0) break;
    BODY(kB, kA, vB, vA); j0 += 32; if (j0 > i0) break;
  }
#undef BODY
#undef SOFTMAX
#undef LOADV
#undef LOADK

  float inv0 = 1.0f / l0, inv1 = 1.0f / l1;
  unsigned short* op0 = ao + ((size_t)(b * SLEN + qi0) * NH + h) * HD;
  unsigned short* op1 = ao + ((size_t)(b * SLEN + qi1) * NH + h) * HD;
#pragma unroll
  for (int vbk = 0; vbk < 4; ++vbk) {
    *(unsigned*)(op0 + vbk * 16 + g * 4)     = cvtpk(acc0[vbk][0] * inv0, acc0[vbk][1] * inv0);
    *(unsigned*)(op0 + vbk * 16 + g * 4 + 2) = cvtpk(acc0[vbk][2] * inv0, acc0[vbk][3] * inv0);
    *(unsigned*)(op1 + vbk * 16 + g * 4)     = cvtpk(acc1[vbk][0] * inv1, acc1[vbk][1] * inv1);
    *(unsigned*)(op1 + vbk * 16 + g * 4 + 2) = cvtpk(acc1[vbk][2] * inv1, acc1[vbk][3] * inv1);
  }
}

// ---------------- launch ---------------------------------------------------
extern "C" void kernel_launch(void* const* d_in, const int* in_sizes, int n_in,
                              void* d_out, int out_size, void* d_ws, size_t ws_size,
                              hipStream_t stream) {
  const float* x  = (const float*)d_in[0];
  const float* wq = (const float*)d_in[1];
  const float* wk = (const float*)d_in[2];
  const float* wv = (const float*)d_in[3];
  const float* wo = (const float*)d_in[4];
  float* out = (float*)d_out;

  char* w = (char*)d_ws;
  unsigned short* wqkvb = (unsigned short*)w; w += (size_t)3136 * 2048 * 2;   // +64 pad rows
  unsigned short* xb    = (unsigned short*)w; w += (size_t)MROWS * QDIM * 2;  // 16 MB
  unsigned short* qb    = (unsigned short*)w; w += (size_t)MROWS * QDIM * 2;  // 16 MB
  unsigned short* kb    = (unsigned short*)w; w += (size_t)MROWS * KVDIM * 2; // 4 MB
  unsigned short* vt    = (unsigned short*)w; w += (size_t)MROWS * KVDIM * 2; // 4 MB
  float* tab            = (float*)w;          w += (size_t)SLEN * 32 * 8;     // 0.5 MB
  // aliases (lifetimes disjoint in stream order):
  unsigned short* wob = wqkvb;   // wo bf16 — written after qkv_gemm reads wqkvb
  unsigned short* ao  = xb;      // attn output — written after qkv_gemm reads xb

  hipFuncSetAttribute((const void*)qkv_gemm,
                      hipFuncAttributeMaxDynamicSharedMemorySize, 131072);
  hipFuncSetAttribute((const void*)out_gemm,
                      hipFuncAttributeMaxDynamicSharedMemorySize, 98304);

  conv_xw<<<7424, 256, 0, stream>>>(x, wq, wk, wv, xb, wqkvb, (float2*)tab);
  qkv_gemm<<<256, 512, 131072, stream>>>(xb, wqkvb, qb, kb, vt);
  post_qkv<<<4608, 256, 0, stream>>>(qb, kb, tab, wo, wob);
  attn<<<(NB * NH * (SLEN / 32)) / 4, 256, 0, stream>>>(qb, kb, vt, ao);
  out_gemm<<<256, 512, 98304, stream>>>(ao, wob, out);
}

// Round 19
// 158.544 us; speedup vs baseline: 1.0133x; 1.0130x over previous
//
#include <hip/hip_runtime.h>
#include <cstdint>
#include <cstddef>

#define SLEN 2048
#define NB 2
#define NH 32
#define NKV 8
#define HD 64
#define MROWS 4096   // NB*SLEN
#define QDIM 2048    // NH*HD
#define KVDIM 512    // NKV*HD
#define WINH 256     // WIN/2

typedef float f32x4 __attribute__((ext_vector_type(4)));
typedef __bf16 bf16x8 __attribute__((ext_vector_type(8)));

__device__ __forceinline__ unsigned short f2bf(float f) {
  union { float f; unsigned u; } v; v.f = f;
  unsigned r = v.u + 0x7fffu + ((v.u >> 16) & 1u);
  return (unsigned short)(r >> 16);
}
__device__ __forceinline__ float bf2f(unsigned short h) {
  union { unsigned u; float f; } v; v.u = ((unsigned)h) << 16;
  return v.f;
}
__device__ __forceinline__ unsigned pk2(float a, float b) {
  return (unsigned)f2bf(a) | ((unsigned)f2bf(b) << 16);
}
// HW packed fp32->bf16 (RNE), 1 inst per pair
__device__ __forceinline__ unsigned cvtpk(float a, float b) {
  unsigned r;
  asm("v_cvt_pk_bf16_f32 %0, %1, %2" : "=v"(r) : "v"(a), "v"(b));
  return r;
}
__device__ __forceinline__ uint4 cvt16(float4 a, float4 b) {
  uint4 u;
  u.x = pk2(a.x, a.y); u.y = pk2(a.z, a.w);
  u.z = pk2(b.x, b.y); u.w = pk2(b.z, b.w);
  return u;
}
// async global->LDS, 16B per lane; LDS dest is wave-uniform base + lane*16
__device__ __forceinline__ void async16(const unsigned short* g, unsigned short* l) {
  __builtin_amdgcn_global_load_lds(
      (const __attribute__((address_space(1))) unsigned int*)g,
      (__attribute__((address_space(3))) unsigned int*)l, 16, 0, 0);
}

// ---------------- merged conversions + RoPE table --------------------------
// units: [0,1048576) x->xb (x8), [.., 1835008) wqkv->wqkvb (x8),
// [.., 1900544) rope table entries.
__global__ void conv_xw(const float* __restrict__ x,
                        const float* __restrict__ wq, const float* __restrict__ wk,
                        const float* __restrict__ wv,
                        unsigned short* __restrict__ xb, unsigned short* __restrict__ wqkvb,
                        float2* __restrict__ tab) {
  size_t t = (size_t)blockIdx.x * 256 + threadIdx.x;   // 1,900,544 units
  if (t < (size_t)1048576) {
    size_t e = t * 8;
    float4 a = *(const float4*)(x + e);
    float4 b = *(const float4*)(x + e + 4);
    *(uint4*)(xb + e) = cvt16(a, b);
  } else if (t < (size_t)1835008) {
    size_t e = (t - 1048576) * 8;
    int row = (int)(e >> 11);
    const float* src; size_t off;
    if (row < 2048)       { src = wq; off = e; }
    else if (row < 2560)  { src = wk; off = e - (size_t)2048 * 2048; }
    else                  { src = wv; off = e - (size_t)2560 * 2048; }
    float4 a = *(const float4*)(src + off);
    float4 b = *(const float4*)(src + off + 4);
    *(uint4*)(wqkvb + e) = cvt16(a, b);
  } else {
    int id = (int)(t - 1835008);       // 65536 entries
    int d = id & 31;
    int s = id >> 5;
    float inv = expf((float)d * (-2.0f / 64.0f) * 9.210340371976184f);
    float ang = (float)s * inv;
    float sn, cs;
    sincosf(ang, &sn, &cs);
    tab[id] = make_float2(cs, sn);
  }
}

// ---------------- RoPE pass on q and k (bf16, vectorized x8) ---------------
__global__ void rope_qk(unsigned short* __restrict__ qb,
                        unsigned short* __restrict__ kb,
                        const float* __restrict__ tabf) {
  const float2* tab = (const float2*)tabf;
  int tid = blockIdx.x * 256 + threadIdx.x;     // 4096*40*4 = 655360
  int oct = tid & 3;
  int head = (tid >> 2) % 40;
  int row = tid / 160;
  int s = row & (SLEN - 1);
  int d0 = oct * 8;
  unsigned short* p = (head < NH)
      ? qb + (size_t)row * QDIM + head * HD
      : kb + (size_t)row * KVDIM + (head - NH) * HD;
  uint4 u0 = *(const uint4*)(p + d0);
  uint4 u1 = *(const uint4*)(p + d0 + 32);
  const unsigned short* a16 = (const unsigned short*)&u0;
  const unsigned short* b16 = (const unsigned short*)&u1;
  unsigned short o0[8], o1[8];
#pragma unroll
  for (int j = 0; j < 8; ++j) {
    float2 cs = tab[s * 32 + d0 + j];
    float a = bf2f(a16[j]), b = bf2f(b16[j]);
    o0[j] = f2bf(a * cs.x - b * cs.y);
    o1[j] = f2bf(b * cs.x + a * cs.y);
  }
  *(uint4*)(p + d0)      = *(const uint4*)o0;
  *(uint4*)(p + d0 + 32) = *(const uint4*)o1;
}

// ======================= QKV GEMM: 256x192, 8-wave, 2-barrier/tile =========
// NOTE: end-of-tile vmcnt(4) is CORRECT and deadline-exact: kh1 ds_reads
// (a01/b1) are register-pipelined BEFORE the mid barrier, so k1(t) must be
// resident by end(t-1). R17's vmcnt(8) raced exactly here (absmax 0.058).
__global__ __launch_bounds__(512, 2) void qkv_gemm(
    const unsigned short* __restrict__ Ap, const unsigned short* __restrict__ Bp,
    unsigned short* __restrict__ o_q, unsigned short* __restrict__ o_k,
    unsigned short* __restrict__ o_v)
{
  extern __shared__ unsigned short L[];
  constexpr int NT = 32;             // K = 2048 / 64

  const int bid = blockIdx.x;        // 256 blocks = 16 M x 16 N
  const int swz = (bid & 7) * 32 + (bid >> 3);   // XCD-aware, bijective
  const int bm0 = (swz & 15) * 256;
  const int bn0 = (swz >> 4) * 192;

  const int tid = threadIdx.x;
  const int lane = tid & 63, wid = tid >> 6;
  const int g = lane >> 4, cl = lane & 15;
  const int wm = wid >> 2, wn = wid & 3;

  const int r0 = wid * 32 + (lane >> 2);
  const int s0 = (((lane & 3) ^ ((lane >> 3) & 3)) << 3);
  const unsigned short* gA = Ap + (size_t)(bm0 + r0) * 2048 + s0;
  const unsigned short* gB = Bp + (size_t)(bn0 + r0) * 2048 + s0;  // padded rows ok

  const int slotus = ((g ^ ((cl >> 1) & 3)) << 3);
  const int aread = (wm * 128 + cl) * 32 + slotus;
  const int bread = (wn * 48 + cl) * 32 + slotus;

#define REG_(b, op, kh) ((((b) * 2 + (op)) * 2 + (kh)) * 8192)
#define STG(op, kh, tt, db) do { \
    const unsigned short* s_ = ((op) ? gB : gA) + (tt) * 64 + (kh) * 32; \
    unsigned short* d_ = L + REG_(db, op, kh) + wid * 1024; \
    async16(s_, d_); \
    async16(s_ + 16 * 2048, d_ + 512); \
  } while (0)
#define LDA(dst, kh, mh) \
    _Pragma("unroll") for (int mf = 0; mf < 4; ++mf) \
      dst[mf] = *(const bf16x8*)&L[REG_(cb, 0, kh) + aread + (mh) * 2048 + mf * 512];
#define LDB(dst, kh) \
    _Pragma("unroll") for (int nf = 0; nf < 3; ++nf) \
      dst[nf] = *(const bf16x8*)&L[REG_(cb, 1, kh) + bread + nf * 512];
#define MM(mh, A, B) do { \
    __builtin_amdgcn_s_setprio(1); \
    _Pragma("unroll") for (int mf = 0; mf < 4; ++mf) \
      _Pragma("unroll") for (int nf = 0; nf < 3; ++nf) \
        acc[(mh) * 4 + mf][nf] = __builtin_amdgcn_mfma_f32_16x16x32_bf16( \
            A[mf], B[nf], acc[(mh) * 4 + mf][nf], 0, 0, 0); \
    __builtin_amdgcn_s_setprio(0); \
  } while (0)

  f32x4 acc[8][3] = {};

  STG(0, 0, 0, 0); STG(1, 0, 0, 0); STG(0, 1, 0, 0); STG(1, 1, 0, 0);
  STG(0, 0, 1, 1); STG(1, 0, 1, 1);
  asm volatile("s_waitcnt vmcnt(4)" ::: "memory");
  __builtin_amdgcn_s_barrier();
  __builtin_amdgcn_sched_barrier(0);

#pragma unroll 1
  for (int t = 0; t < NT; ++t) {
    const int cb = t & 1, nb = cb ^ 1;
    bf16x8 a00[4], a10[4], a01[4], a11[4], b0[3], b1[3];

    if (t + 1 < NT) STG(0, 1, t + 1, nb);
    LDA(a00, 0, 0); LDB(b0, 0);
    if (t + 1 < NT) STG(1, 1, t + 1, nb);
    LDA(a10, 0, 1);
    MM(0, a00, b0);
    LDA(a01, 1, 0); LDB(b1, 1);
    MM(1, a10, b0);
    asm volatile("s_waitcnt lgkmcnt(0)" ::: "memory");
    __builtin_amdgcn_s_barrier();               // mid: k0(cb) free to overwrite
    __builtin_amdgcn_sched_barrier(0);
    if (t + 2 < NT) STG(0, 0, t + 2, cb);
    LDA(a11, 1, 1);
    MM(0, a01, b1);
    if (t + 2 < NT) STG(1, 0, t + 2, cb);
    MM(1, a11, b1);
    if (t + 2 < NT) { asm volatile("s_waitcnt vmcnt(4)" ::: "memory"); }
    else            { asm volatile("s_waitcnt vmcnt(0)" ::: "memory"); }
    asm volatile("s_waitcnt lgkmcnt(0)" ::: "memory");
    __builtin_amdgcn_s_barrier();               // end: tile t+1 published
    __builtin_amdgcn_sched_barrier(0);
  }
#undef MM
#undef LDB
#undef LDA
#undef STG
#undef REG_

  // ---------------- epilogue: direct stores (q / k / v^T) ------------------
  const int rb = bm0 + wm * 128;
#pragma unroll
  for (int m = 0; m < 8; ++m)
#pragma unroll
    for (int nf = 0; nf < 3; ++nf) {
      const int col = bn0 + wn * 48 + nf * 16 + cl;
      if (col < QDIM) {
#pragma unroll
        for (int p = 0; p < 4; ++p) {
          int row = rb + m * 16 + g * 4 + p;
          o_q[(size_t)row * QDIM + col] = f2bf(acc[m][nf][p]);
        }
      } else if (col < QDIM + KVDIM) {
#pragma unroll
        for (int p = 0; p < 4; ++p) {
          int row = rb + m * 16 + g * 4 + p;
          o_k[(size_t)row * KVDIM + col - QDIM] = f2bf(acc[m][nf][p]);
        }
      } else {
        int vc = col - QDIM - KVDIM;            // kvh*64 + d
        int kvh = vc >> 6, d = vc & 63;
        int row0 = rb + m * 16 + g * 4;
        int bb = row0 >> 11, s = row0 & (SLEN - 1);
        unsigned short* dst = o_v + (((size_t)(bb * NKV + kvh) * HD + d) << 11) + s;
        uint2 u;
        u.x = pk2(acc[m][nf][0], acc[m][nf][1]);
        u.y = pk2(acc[m][nf][2], acc[m][nf][3]);
        *(uint2*)dst = u;
      }
    }
}

// ======================= OUT GEMM: 128x256, 8-wave, 2-barrier/tile =========
__global__ __launch_bounds__(512, 2) void out_gemm(
    const unsigned short* __restrict__ Ap, const unsigned short* __restrict__ Bp,
    float* __restrict__ o_f)
{
  extern __shared__ unsigned short L[];
  constexpr int NT = 32;

  const int bid = blockIdx.x;        // 256 blocks (32 x 8)
  const int swz = (bid & 7) * 32 + (bid >> 3);
  const int bm0 = (swz & 31) * 128;
  const int bn0 = (swz >> 5) * 256;

  const int tid = threadIdx.x;
  const int lane = tid & 63, wid = tid >> 6;
  const int g = lane >> 4, cl = lane & 15;
  const int wm = wid >> 2, wn = wid & 3;

  const int s0 = (((lane & 3) ^ ((lane >> 3) & 3)) << 3);
  const unsigned short* gA = Ap + (size_t)(bm0 + wid * 16 + (lane >> 2)) * 2048 + s0;
  const unsigned short* gB = Bp + (size_t)(bn0 + wid * 32 + (lane >> 2)) * 2048 + s0;

  const int slotus = ((g ^ ((cl >> 1) & 3)) << 3);
  const int aread = (wm * 64 + cl) * 32 + slotus;
  const int bread = (wn * 64 + cl) * 32 + slotus;

#define REGA_(b, kh) ((b) * 24576 + (kh) * 4096)
#define REGB_(b, kh) ((b) * 24576 + 8192 + (kh) * 8192)
#define STGA(kh, tt, db) \
    async16(gA + (tt) * 64 + (kh) * 32, L + REGA_(db, kh) + wid * 512)
#define STGB(kh, tt, db) do { \
    const unsigned short* s_ = gB + (tt) * 64 + (kh) * 32; \
    unsigned short* d_ = L + REGB_(db, kh) + wid * 1024; \
    async16(s_, d_); \
    async16(s_ + 16 * 2048, d_ + 512); \
  } while (0)
#define LA(dst, kh, mp) \
    _Pragma("unroll") for (int mf = 0; mf < 2; ++mf) \
      dst[mf] = *(const bf16x8*)&L[REGA_(cb, kh) + aread + (mp) * 1024 + mf * 512];
#define LB(dst, kh) \
    _Pragma("unroll") for (int nf = 0; nf < 4; ++nf) \
      dst[nf] = *(const bf16x8*)&L[REGB_(cb, kh) + bread + nf * 512];
#define MMO(mp, A, B) do { \
    __builtin_amdgcn_s_setprio(1); \
    _Pragma("unroll") for (int mf = 0; mf < 2; ++mf) \
      _Pragma("unroll") for (int nf = 0; nf < 4; ++nf) \
        acc[(mp) * 2 + mf][nf] = __builtin_amdgcn_mfma_f32_16x16x32_bf16( \
            A[mf], B[nf], acc[(mp) * 2 + mf][nf], 0, 0, 0); \
    __builtin_amdgcn_s_setprio(0); \
  } while (0)

  f32x4 acc[4][4] = {};

  STGA(0, 0, 0); STGB(0, 0, 0); STGA(1, 0, 0); STGB(1, 0, 0);
  STGA(0, 1, 1); STGB(0, 1, 1);
  asm volatile("s_waitcnt vmcnt(3)" ::: "memory");
  __builtin_amdgcn_s_barrier();
  __builtin_amdgcn_sched_barrier(0);

#pragma unroll 1
  for (int t = 0; t < NT; ++t) {
    const int cb = t & 1, nb = cb ^ 1;
    bf16x8 p00[2], p10[2], p01[2], p11[2], b0[4], b1[4];

    if (t + 1 < NT) STGA(1, t + 1, nb);
    LA(p00, 0, 0); LB(b0, 0);
    if (t + 1 < NT) STGB(1, t + 1, nb);
    LA(p10, 0, 1);
    MMO(0, p00, b0);
    LA(p01, 1, 0); LB(b1, 1);
    MMO(1, p10, b0);
    asm volatile("s_waitcnt lgkmcnt(0)" ::: "memory");
    __builtin_amdgcn_s_barrier();
    __builtin_amdgcn_sched_barrier(0);
    if (t + 2 < NT) STGA(0, t + 2, cb);
    LA(p11, 1, 1);
    MMO(0, p01, b1);
    if (t + 2 < NT) STGB(0, t + 2, cb);
    MMO(1, p11, b1);
    if (t + 2 < NT) { asm volatile("s_waitcnt vmcnt(3)" ::: "memory"); }
    else            { asm volatile("s_waitcnt vmcnt(0)" ::: "memory"); }
    asm volatile("s_waitcnt lgkmcnt(0)" ::: "memory");
    __builtin_amdgcn_s_barrier();
    __builtin_amdgcn_sched_barrier(0);
  }
#undef MMO
#undef LB
#undef LA
#undef STGB
#undef STGA
#undef REGB_
#undef REGA_

  const int rb = bm0 + wm * 64;
  const int colb = bn0 + wn * 64;
#pragma unroll
  for (int m = 0; m < 4; ++m)
#pragma unroll
    for (int nf = 0; nf < 4; ++nf)
#pragma unroll
      for (int p = 0; p < 4; ++p) {
        int row = rb + m * 16 + g * 4 + p;
        o_f[(size_t)row * 2048 + colb + nf * 16 + cl] = acc[m][nf][p];
      }
}

// ---- Flash attention (blocks 0..1023) + wo->bf16 conversion (1024..3071) --
// attn is latency-bound (~35% occupancy); the memory-bound conversion blocks
// co-reside and fill idle issue slots, hiding the wo conversion entirely.
// attn has no __syncthreads, so the block-uniform early path is safe.
__global__ __launch_bounds__(256) void attn(
    const unsigned short* __restrict__ qb, const unsigned short* __restrict__ kb,
    const unsigned short* __restrict__ vt, unsigned short* __restrict__ ao,
    const float* __restrict__ wo, unsigned short* __restrict__ wob)
{
  if (blockIdx.x >= 1024) {
    size_t t = (size_t)(blockIdx.x - 1024) * 256 + threadIdx.x;  // 524288 units
    size_t e = t * 8;
    float4 a = *(const float4*)(wo + e);
    float4 b = *(const float4*)(wo + e + 4);
    *(uint4*)(wob + e) = cvt16(a, b);
    return;
  }

  __shared__ __align__(16) unsigned short Plds[4][2][16][40];
  const int lane = threadIdx.x & 63, wid = threadIdx.x >> 6;
  const int g = lane >> 4, cl = lane & 15;
  const int qt = blockIdx.x * 4 + wid;         // 0..4095 tiles of 32 queries
  const int bh = qt >> 6, tl = qt & 63;
  const int i0 = tl * 32;
  const int b = bh >> 5, h = bh & 31, kvh = (bh & 31) >> 2;
  const int qi0 = i0 + cl, qi1 = i0 + 16 + cl;

  const unsigned short* qp0 = qb + ((size_t)(b * SLEN + qi0) * NH + h) * HD + g * 8;
  const unsigned short* qp1 = qb + ((size_t)(b * SLEN + qi1) * NH + h) * HD + g * 8;
  bf16x8 qf00 = *(const bf16x8*)qp0, qf01 = *(const bf16x8*)(qp0 + 32);
  bf16x8 qf10 = *(const bf16x8*)qp1, qf11 = *(const bf16x8*)(qp1 + 32);

  const unsigned short* kbase = kb + ((size_t)b * SLEN * NKV + kvh) * HD + g * 8;
  const unsigned short* vbase = vt + ((size_t)(b * NKV + kvh) * HD) * SLEN;

  f32x4 acc0[4] = {}, acc1[4] = {};
  float m0 = -1e30f, l0 = 0.f, m1 = -1e30f, l1 = 0.f;
  const int jb = (i0 > WINH) ? (i0 - WINH) : 0;

#define LOADK(dst, jj) do { \
    _Pragma("unroll") for (int t = 0; t < 2; ++t) { \
      int krow = (jj) + 16 * t + cl; \
      if (krow > SLEN - 1) krow = SLEN - 1; \
      const unsigned short* kp_ = kbase + (size_t)krow * KVDIM; \
      dst[t * 2]     = *(const bf16x8*)kp_; \
      dst[t * 2 + 1] = *(const bf16x8*)(kp_ + 32); \
    } \
  } while (0)

#define LOADV(dst, jj) do { \
    int jv = (jj) + g * 8; \
    if (jv > SLEN - 8) jv = SLEN - 8; \
    _Pragma("unroll") for (int vb2 = 0; vb2 < 4; ++vb2) \
      dst[vb2] = *(const bf16x8*)(vbase + (size_t)(vb2 * 16 + cl) * SLEN + jv); \
  } while (0)

#define SOFTMAX(SAC, MR, LR, ACC, QI, QF) do { \
    float sm[2][4]; float mx = -1e30f; \
    _Pragma("unroll") for (int t = 0; t < 2; ++t) \
      _Pragma("unroll") for (int p = 0; p < 4; ++p) { \
        int kj = j0 + 16 * t + 4 * g + p; \
        bool ok = (kj <= (QI)) && ((QI) - kj <= WINH); \
        float v = ok ? SAC[t][p] * 0.125f : -1e30f; \
        sm[t][p] = v; mx = fmaxf(mx, v); \
      } \
    mx = fmaxf(mx, __shfl_xor(mx, 16)); \
    mx = fmaxf(mx, __shfl_xor(mx, 32)); \
    float mnew = fmaxf(MR, mx); \
    float corr = __expf(MR - mnew); \
    float ps = 0.f; unsigned pw00, pw01, pw10, pw11; \
    { \
      float p0 = __expf(sm[0][0] - mnew), p1 = __expf(sm[0][1] - mnew); \
      float p2 = __expf(sm[0][2] - mnew), p3 = __expf(sm[0][3] - mnew); \
      ps += p0 + p1 + p2 + p3; pw00 = cvtpk(p0, p1); pw01 = cvtpk(p2, p3); \
      float p4 = __expf(sm[1][0] - mnew), p5 = __expf(sm[1][1] - mnew); \
      float p6 = __expf(sm[1][2] - mnew), p7 = __expf(sm[1][3] - mnew); \
      ps += p4 + p5 + p6 + p7; pw10 = cvtpk(p4, p5); pw11 = cvtpk(p6, p7); \
    } \
    ps += __shfl_xor(ps, 16); ps += __shfl_xor(ps, 32); \
    LR = LR * corr + ps; MR = mnew; \
    _Pragma("unroll") for (int vb2 = 0; vb2 < 4; ++vb2) \
      _Pragma("unroll") for (int p = 0; p < 4; ++p) ACC[vb2][p] *= corr; \
    *(unsigned*)&Plds[wid][QF][cl][4 * g]          = pw00; \
    *(unsigned*)&Plds[wid][QF][cl][4 * g + 2]      = pw01; \
    *(unsigned*)&Plds[wid][QF][cl][16 + 4 * g]     = pw10; \
    *(unsigned*)&Plds[wid][QF][cl][16 + 4 * g + 2] = pw11; \
  } while (0)

#define BODY(KC, KN, VC, VN) do { \
    LOADK(KN, j0 + 32);                          /* prefetch next K tile */ \
    LOADV(VN, j0 + 32);                          /* prefetch next V tile */ \
    f32x4 s0[2], s1[2]; \
    _Pragma("unroll") for (int t = 0; t < 2; ++t) { \
      f32x4 z = {}; \
      z = __builtin_amdgcn_mfma_f32_16x16x32_bf16(KC[t * 2], qf00, z, 0, 0, 0); \
      z = __builtin_amdgcn_mfma_f32_16x16x32_bf16(KC[t * 2 + 1], qf01, z, 0, 0, 0); \
      s0[t] = z; \
      f32x4 z2 = {}; \
      z2 = __builtin_amdgcn_mfma_f32_16x16x32_bf16(KC[t * 2], qf10, z2, 0, 0, 0); \
      z2 = __builtin_amdgcn_mfma_f32_16x16x32_bf16(KC[t * 2 + 1], qf11, z2, 0, 0, 0); \
      s1[t] = z2; \
    } \
    SOFTMAX(s0, m0, l0, acc0, qi0, 0); \
    SOFTMAX(s1, m1, l1, acc1, qi1, 1); \
    bf16x8 pf0 = *(const bf16x8*)&Plds[wid][0][cl][g * 8]; \
    bf16x8 pf1 = *(const bf16x8*)&Plds[wid][1][cl][g * 8]; \
    _Pragma("unroll") for (int vb2 = 0; vb2 < 4; ++vb2) \
      acc0[vb2] = __builtin_amdgcn_mfma_f32_16x16x32_bf16(VC[vb2], pf0, acc0[vb2], 0, 0, 0); \
    _Pragma("unroll") for (int vb2 = 0; vb2 < 4; ++vb2) \
      acc1[vb2] = __builtin_amdgcn_mfma_f32_16x16x32_bf16(VC[vb2], pf1, acc1[vb2], 0, 0, 0); \
  } while (0)

  bf16x8 kA[4], kB[4], vA[4], vB[4];
  LOADK(kA, jb); LOADV(vA, jb);
  int j0 = jb;
  for (;;) {
    BODY(kA, kB, vA, vB); j0 += 32; if (j0 > i0) break;
    BODY(kB, kA, vB, vA); j0 += 32; if (j0 > i0) break;
  }
#undef BODY
#undef SOFTMAX
#undef LOADV
#undef LOADK

  float inv0 = 1.0f / l0, inv1 = 1.0f / l1;
  unsigned short* op0 = ao + ((size_t)(b * SLEN + qi0) * NH + h) * HD;
  unsigned short* op1 = ao + ((size_t)(b * SLEN + qi1) * NH + h) * HD;
#pragma unroll
  for (int vbk = 0; vbk < 4; ++vbk) {
    *(unsigned*)(op0 + vbk * 16 + g * 4)     = cvtpk(acc0[vbk][0] * inv0, acc0[vbk][1] * inv0);
    *(unsigned*)(op0 + vbk * 16 + g * 4 + 2) = cvtpk(acc0[vbk][2] * inv0, acc0[vbk][3] * inv0);
    *(unsigned*)(op1 + vbk * 16 + g * 4)     = cvtpk(acc1[vbk][0] * inv1, acc1[vbk][1] * inv1);
    *(unsigned*)(op1 + vbk * 16 + g * 4 + 2) = cvtpk(acc1[vbk][2] * inv1, acc1[vbk][3] * inv1);
  }
}

// ---------------- launch ---------------------------------------------------
extern "C" void kernel_launch(void* const* d_in, const int* in_sizes, int n_in,
                              void* d_out, int out_size, void* d_ws, size_t ws_size,
                              hipStream_t stream) {
  const float* x  = (const float*)d_in[0];
  const float* wq = (const float*)d_in[1];
  const float* wk = (const float*)d_in[2];
  const float* wv = (const float*)d_in[3];
  const float* wo = (const float*)d_in[4];
  float* out = (float*)d_out;

  char* w = (char*)d_ws;
  unsigned short* wqkvb = (unsigned short*)w; w += (size_t)3136 * 2048 * 2;   // +64 pad rows
  unsigned short* xb    = (unsigned short*)w; w += (size_t)MROWS * QDIM * 2;  // 16 MB
  unsigned short* qb    = (unsigned short*)w; w += (size_t)MROWS * QDIM * 2;  // 16 MB
  unsigned short* kb    = (unsigned short*)w; w += (size_t)MROWS * KVDIM * 2; // 4 MB
  unsigned short* vt    = (unsigned short*)w; w += (size_t)MROWS * KVDIM * 2; // 4 MB
  float* tab            = (float*)w;          w += (size_t)SLEN * 32 * 8;     // 0.5 MB
  // aliases (lifetimes disjoint in stream order):
  unsigned short* wob = wqkvb;   // wo bf16 — written (in attn dispatch) after qkv_gemm reads wqkvb
  unsigned short* ao  = xb;      // attn output — written after qkv_gemm reads xb

  hipFuncSetAttribute((const void*)qkv_gemm,
                      hipFuncAttributeMaxDynamicSharedMemorySize, 131072);
  hipFuncSetAttribute((const void*)out_gemm,
                      hipFuncAttributeMaxDynamicSharedMemorySize, 98304);

  conv_xw<<<7424, 256, 0, stream>>>(x, wq, wk, wv, xb, wqkvb, (float2*)tab);
  qkv_gemm<<<256, 512, 131072, stream>>>(xb, wqkvb, qb, kb, vt);
  rope_qk<<<(MROWS * 40 * 4) / 256, 256, 0, stream>>>(qb, kb, tab);
  attn<<<3072, 256, 0, stream>>>(qb, kb, vt, ao, wo, wob);
  out_gemm<<<256, 512, 98304, stream>>>(ao, wob, out);
}